// Round 9
// baseline (146.637 us; speedup 1.0000x reference)
//
#include <hip/hip_runtime.h>
#include <math.h>

#define TSEQ 2048
#define NB 4
#define DM 512
#define NH 8
#define HD 64

typedef _Float16 half8 __attribute__((ext_vector_type(8)));
typedef _Float16 half4 __attribute__((ext_vector_type(4)));
typedef float floatx4 __attribute__((ext_vector_type(4)));

#if __has_builtin(__builtin_amdgcn_exp2f)
#define EXP2F(x) __builtin_amdgcn_exp2f(x)
#else
#define EXP2F(x) exp2f(x)
#endif

// async 16B global->LDS DMA (lane-linear LDS dest: uniform base + lane*16)
__device__ __forceinline__ void gl2lds16(const _Float16* g, _Float16* l) {
  const __attribute__((address_space(1))) unsigned int* gp =
      (const __attribute__((address_space(1))) unsigned int*)(uintptr_t)g;
  __attribute__((address_space(3))) unsigned int* lp =
      (__attribute__((address_space(3))) unsigned int*)(uintptr_t)l;
  __builtin_amdgcn_global_load_lds(gp, lp, 16, 0, 0);
}

// ws layout (bytes):
//   [0,         8388608)  (xh region UNUSED -- x-cvt fused into qkv)
//   [8650752,  10223616)  wqkvh   (f16 Wqkv)
//   [10485760, 11010048)  owh     (f16 out_w)
//   [11534336, 19922944)  qbuf
//   [20971520, 29360128)  kbuf
//   [29360128, 37748736)  vTb
//   [37748736, 46137344)  ctxh
//   [46137344, 46661632)  rope table (float2 [t][i])

__device__ __forceinline__ void cvt8(const float* __restrict__ src, char* __restrict__ dst,
                                     int unit_src, int unit_dst) {
  const float4 a = ((const float4*)src)[2 * unit_src];
  const float4 b = ((const float4*)src)[2 * unit_src + 1];
  half8 h;
  h[0] = (_Float16)a.x; h[1] = (_Float16)a.y; h[2] = (_Float16)a.z; h[3] = (_Float16)a.w;
  h[4] = (_Float16)b.x; h[5] = (_Float16)b.y; h[6] = (_Float16)b.z; h[7] = (_Float16)b.w;
  *(half8*)(dst + (size_t)unit_dst * 16) = h;
}

// Units of 16B: wqkvh 98304 | owh 32768 | rope 32768 = 163840 total
__global__ void prep(const float* __restrict__ wqkv,
                     const float* __restrict__ ow, char* __restrict__ ws) {
  const int i = blockIdx.x * 256 + threadIdx.x;   // grid exactly covers 163840
  if (i < 98304) {                          // wqkvh
    cvt8(wqkv, ws + 8650752, i, i);
  } else if (i < 131072) {                  // owh
    const int o = i - 98304;
    cvt8(ow, ws + 10485760, o, o);
  } else {                                  // rope table: 2 entries per 16B unit
    const int u = i - 131072;
    float4 o4;
    {
      const int id = 2 * u, t = id >> 5, fi = id & 31;
      const float invf = powf(10000.0f, -(float)(2 * fi) * (1.0f / 64.0f));
      float s, c; sincosf((float)t * invf, &s, &c);
      o4.x = c; o4.y = s;
    }
    {
      const int id = 2 * u + 1, t = id >> 5, fi = id & 31;
      const float invf = powf(10000.0f, -(float)(2 * fi) * (1.0f / 64.0f));
      float s, c; sincosf((float)t * invf, &s, &c);
      o4.z = c; o4.w = s;
    }
    ((float4*)(ws + 46137344))[u] = o4;
  }
}

// ---------------- QKV GEMM (f16 MFMA) + fused RoPE -----------------------------
// R8 dbuf pipeline + fused x f32->f16 staging (reg-stage A: f32 loads issued
// one compute-phase early, cvt + ds_write at stage time). B keeps
// global_load_lds. R14 FIX: prefetch clamps use DM-32 (last valid 32-wide K
// tile), not DM-64 -- R13 staged tile 480 with tile 448's data.
__global__ __launch_bounds__(256) void qkv_gemm_mfma(
    const float* __restrict__ X, const _Float16* __restrict__ B,
    const float2* __restrict__ rope,
    _Float16* __restrict__ qb, _Float16* __restrict__ kb, _Float16* __restrict__ vT)
{
  __shared__ __align__(16) _Float16 As0[128 * 32];
  __shared__ __align__(16) _Float16 Bs0[128 * 32];
  __shared__ __align__(16) _Float16 As1[128 * 32];
  __shared__ __align__(16) _Float16 Bs1[128 * 32];
  const int tid = threadIdx.x;
  const int wv = tid >> 6, lane = tid & 63, quad = lane >> 4, col = lane & 15;
  const int wm = wv >> 1, we = wv & 1;
  const int m0 = blockIdx.x << 7, c0 = blockIdx.y << 7;
  const int r0 = tid >> 2, p0 = tid & 3;
  const int cA0 = (p0 - (r0 >> 1)) & 3;
  const int r1 = (tid + 256) >> 2, p1 = tid & 3;
  const int cA1 = (p1 - (r1 >> 1)) & 3;
  const float* gx0 = &X[(size_t)(m0 + r0) * DM + cA0 * 8];
  const float* gx1 = &X[(size_t)(m0 + r1) * DM + cA1 * 8];
  const _Float16* gb0 = &B[(size_t)(c0 + r0) * DM + cA0 * 8];
  const _Float16* gb1 = &B[(size_t)(c0 + r1) * DM + cA1 * 8];
  floatx4 acc[4][4] = {};   // [mt][et]
  float4 fa0, fa1, fa2, fa3;      // in-flight f32 A data for the NEXT stage

#define A_LOAD(K)                                    \
  do {                                               \
    const float* p0_ = gx0 + (K);                    \
    const float* p1_ = gx1 + (K);                    \
    fa0 = *(const float4*)p0_;                       \
    fa1 = *(const float4*)(p0_ + 4);                 \
    fa2 = *(const float4*)p1_;                       \
    fa3 = *(const float4*)(p1_ + 4);                 \
  } while (0)

#define A_WRITE(AS)                                                        \
  do {                                                                     \
    half8 h0_, h1_;                                                        \
    h0_[0] = (_Float16)fa0.x; h0_[1] = (_Float16)fa0.y;                    \
    h0_[2] = (_Float16)fa0.z; h0_[3] = (_Float16)fa0.w;                    \
    h0_[4] = (_Float16)fa1.x; h0_[5] = (_Float16)fa1.y;                    \
    h0_[6] = (_Float16)fa1.z; h0_[7] = (_Float16)fa1.w;                    \
    h1_[0] = (_Float16)fa2.x; h1_[1] = (_Float16)fa2.y;                    \
    h1_[2] = (_Float16)fa2.z; h1_[3] = (_Float16)fa2.w;                    \
    h1_[4] = (_Float16)fa3.x; h1_[5] = (_Float16)fa3.y;                    \
    h1_[6] = (_Float16)fa3.z; h1_[7] = (_Float16)fa3.w;                    \
    *(half8*)&AS[tid * 8] = h0_;                                           \
    *(half8*)&AS[(tid + 256) * 8] = h1_;                                   \
  } while (0)

#define B_STAGE(BS, K)                               \
  do {                                               \
    gl2lds16(gb0 + (K), &BS[tid * 8]);               \
    gl2lds16(gb1 + (K), &BS[(tid + 256) * 8]);       \
  } while (0)

#define QKV_COMPUTE(AS, BS)                                                   \
  do {                                                                        \
    half8 af[4], bf[4];                                                       \
    _Pragma("unroll") for (int mt = 0; mt < 4; mt++) {                        \
      const int R = wm * 64 + mt * 16 + col;                                  \
      af[mt] = *(const half8*)&AS[R * 32 + (((quad + (R >> 1)) & 3) << 3)];   \
    }                                                                         \
    _Pragma("unroll") for (int et = 0; et < 4; et++) {                        \
      const int R = we * 64 + et * 16 + col;                                  \
      bf[et] = *(const half8*)&BS[R * 32 + (((quad + (R >> 1)) & 3) << 3)];   \
    }                                                                         \
    _Pragma("unroll") for (int mt = 0; mt < 4; mt++)                          \
      _Pragma("unroll") for (int et = 0; et < 4; et++)                        \
        acc[mt][et] =                                                         \
            __builtin_amdgcn_mfma_f32_16x16x32_f16(af[mt], bf[et], acc[mt][et], 0, 0, 0); \
  } while (0)

  // prologue: tile 0 staged (A latency exposed once), tile 1's A in flight
  A_LOAD(0);
  A_WRITE(As0);
  B_STAGE(Bs0, 0);
  A_LOAD(32);
  for (int k0 = 0; k0 < DM; k0 += 64) {
    __syncthreads();                    // buf0(k0) landed & visible; prev reads done
    A_WRITE(As1);                       // fa holds k0+32 (loaded a phase ago)
    B_STAGE(Bs1, k0 + 32);
    A_LOAD(min(k0 + 64, DM - 32));      // clamp to LAST VALID tile (dead if past end)
    QKV_COMPUTE(As0, Bs0);
    __syncthreads();                    // buf1 landed & visible; buf0 reads done
    if (k0 + 64 < DM) {
      A_WRITE(As0);                     // fa holds k0+64
      B_STAGE(Bs0, k0 + 64);
    }
    A_LOAD(min(k0 + 96, DM - 32));      // feeds next iter's As1 (tile k0+96)
    QKV_COMPUTE(As1, Bs1);
  }
#undef A_LOAD
#undef A_WRITE
#undef B_STAGE
#undef QKV_COMPUTE

  const int eidx = (c0 >> 6) + we;            // 0..23, wave-uniform
  const int three = eidx >> 3, h = eidx & 7;
  const int mbase = m0 + wm * 64 + quad * 4;
  if (three == 2) {
#pragma unroll
    for (int mt = 0; mt < 4; mt++) {
      const int m = mbase + mt * 16;
      const int n = m >> 11, t = m & 2047;
#pragma unroll
      for (int et = 0; et < 4; et++) {
        const int dh = et * 16 + col;
        half4 hv;
#pragma unroll
        for (int r = 0; r < 4; r++) hv[r] = (_Float16)acc[mt][et][r];
        *(half4*)&vT[(size_t)(n * NH + h) * HD * TSEQ + (size_t)dh * TSEQ + t] = hv;
      }
    }
  } else {
    _Float16* dst = three ? kb : qb;
    // q scale = (1/8) * log2(e) so attention's exp is a bare v_exp_f32
    const float scl = three ? 1.0f : 0.125f * 1.4426950408889634f;
#pragma unroll
    for (int mt = 0; mt < 4; mt++)
#pragma unroll
      for (int r = 0; r < 4; r++) {
        const int m = mbase + mt * 16 + r;
        const int n = m >> 11, t = m & 2047;
#pragma unroll
        for (int et = 0; et < 4; et++) {
          const int i = ((et & 1) << 4) + col;
          const float2 cs = rope[t * 32 + i];
          const float v = acc[mt][et][r];
          const float v2 = acc[mt][et ^ 2][r];
          const float o = (et < 2) ? (v * cs.x - v2 * cs.y) : (v * cs.x + v2 * cs.y);
          dst[((size_t)(n * NH + h) * TSEQ + t) * HD + et * 16 + col] = (_Float16)(o * scl);
        }
      }
  }
}

// ---------------- windowed flash attention, shift-free softmax ----------------
// R12 (kept): QBLK=128, 8 waves, 6 tiles/block, wave-uniform tile+subtile skip,
// XCD swizzle, reg prefetch, 2 barriers/tile.
__global__ __launch_bounds__(512, 4) void attn_win_mfma(
    const _Float16* __restrict__ qb, const _Float16* __restrict__ kb,
    const _Float16* __restrict__ vT, _Float16* __restrict__ ctx)
{
  __shared__ __align__(16) char smem[55296];
  _Float16* Ks = (_Float16*)smem;              // [64][72] j-major
  _Float16* Vt = (_Float16*)(smem + 9216);     // [64][72] d-major (from vT global)
  _Float16* Ps = (_Float16*)(smem + 18432);    // [128][72] i-major (wave-private rows)
  _Float16* Osh = (_Float16*)(smem + 36864);   // [128][72]

  const int tid = threadIdx.x;
  const int wv = tid >> 6;                     // 0..7
  const int lane = tid & 63;
  const int quad = lane >> 4;
  const int col = lane & 15;
  // XCD swizzle: lin%8 = XCD -> 64 contiguous sl per XCD = 4 batch-heads
  const int lin = (blockIdx.y << 4) | blockIdx.x;          // 0..511
  const int sl  = ((lin & 7) << 6) | (lin >> 3);
  const int nh = sl >> 4;
  const int q0 = (sl & 15) << 7;
  const _Float16* qp = qb + (size_t)nh * TSEQ * HD;
  const _Float16* kp = kb + (size_t)nh * TSEQ * HD;
  const _Float16* vp = vT + (size_t)nh * HD * TSEQ;

  const int i_row = (wv << 4) + col;           // 0..127
  const int ig = q0 + i_row;
  const half8 qf0 = *(const half8*)&qp[(size_t)ig * HD + (quad << 3)];
  const half8 qf1 = *(const half8*)&qp[(size_t)ig * HD + 32 + (quad << 3)];

  float l_i = 0.0f;          // per-lane partial sum of p
  floatx4 accO[4] = {};

  const int kt0 = max(0, q0 - 127) >> 6;
  const int kt1 = min(TSEQ - 1, q0 + 255) >> 6;
  // staging: 512 threads cover one 64x64 f16 tile at 16B/thread
  const int kr = tid >> 3, kc = (tid & 7) << 3;      // row 0..63, col-chunk 0..56
  const _Float16* kpr = kp + (size_t)kr * HD + kc;   // + j0*HD selects K tile
  const _Float16* vpr = vp + (size_t)kr * TSEQ + kc; // + j0 selects V^T tile
  const int iw0 = q0 + (wv << 4);                    // wave's first query

  // prologue: load first tile into registers
  half8 ck = *(const half8*)(kpr + (size_t)(kt0 << 6) * HD);
  half8 cv = *(const half8*)(vpr + (kt0 << 6));

  for (int kt = kt0; kt <= kt1; kt++) {
    const int j0 = kt << 6;
    __syncthreads();   // previous iteration's LDS reads complete
    *(half8*)&Ks[kr * 72 + kc] = ck;
    *(half8*)&Vt[kr * 72 + kc] = cv;
    __syncthreads();   // staging visible

    // prefetch NEXT tile into registers; latency hides under compute below.
    {
      const int jn = (kt < kt1) ? (j0 + 64) : j0;
      ck = *(const half8*)(kpr + (size_t)jn * HD);
      cv = *(const half8*)(vpr + jn);
    }

    // wave-uniform whole-tile skip: tile [j0, j0+63] intersects wave window
    // [iw0-127, iw0+143] iff j0 in [iw0-190, iw0+143]
    if ((unsigned)(j0 - iw0 + 190) >= 334u) continue;

    // live(js): subtile [jlo, jlo+15] intersects [iw0-127, iw0+143]
    // <=> (unsigned)(jlo - iw0 + 142) < 286
    // S^T[j][i]: A = K rows, B = Q^T. C-layout: row=j_local, col=i(=our query)
    floatx4 S[4];
#pragma unroll
    for (int js = 0; js < 4; js++) {
      const int jlo = j0 + (js << 4);
      if ((unsigned)(jlo - iw0 + 142) < 286u) {
        const half8 a0 = *(const half8*)&Ks[((js << 4) + col) * 72 + (quad << 3)];
        const half8 a1 = *(const half8*)&Ks[((js << 4) + col) * 72 + 32 + (quad << 3)];
        floatx4 c = {0.f, 0.f, 0.f, 0.f};
        c = __builtin_amdgcn_mfma_f32_16x16x32_f16(a0, qf0, c, 0, 0, 0);
        c = __builtin_amdgcn_mfma_f32_16x16x32_f16(a1, qf1, c, 0, 0, 0);
        S[js] = c;
      }
    }
    // mask -> p = exp2(s) (q carries log2e/8); masked p = 0. No max, no rescale.
    // window test: j in [ig-127, ig+128]  <=>  (unsigned)(j - ig + 127) < 256
    const int relb = j0 - ig + 127 + (quad << 2);
#pragma unroll
    for (int js = 0; js < 4; js++) {
      const int jlo = j0 + (js << 4);
      if ((unsigned)(jlo - iw0 + 142) < 286u) {
        half4 ph;
#pragma unroll
        for (int r = 0; r < 4; r++) {
          const bool valid = (unsigned)(relb + (js << 4) + r) < 256u;
          const float p = valid ? EXP2F(S[js][r]) : 0.0f;
          l_i += p;
          ph[r] = (_Float16)p;
        }
        *(half4*)&Ps[i_row * 72 + (js << 4) + (quad << 2)] = ph;
      } else {
        const half4 zz = {(_Float16)0.f, (_Float16)0.f, (_Float16)0.f, (_Float16)0.f};
        *(half4*)&Ps[i_row * 72 + (js << 4) + (quad << 2)] = zz;
      }
    }
    // PV directly: Ps rows are wave-private; same-wave LDS ordering suffices.
    const half8 pa0 = *(const half8*)&Ps[i_row * 72 + (quad << 3)];
    const half8 pa1 = *(const half8*)&Ps[i_row * 72 + 32 + (quad << 3)];
#pragma unroll
    for (int d4 = 0; d4 < 4; d4++) {
      const half8 vb0 = *(const half8*)&Vt[((d4 << 4) + col) * 72 + (quad << 3)];
      const half8 vb1 = *(const half8*)&Vt[((d4 << 4) + col) * 72 + 32 + (quad << 3)];
      accO[d4] = __builtin_amdgcn_mfma_f32_16x16x32_f16(pa0, vb0, accO[d4], 0, 0, 0);
      accO[d4] = __builtin_amdgcn_mfma_f32_16x16x32_f16(pa1, vb1, accO[d4], 0, 0, 0);
    }
  }
  // one cross-lane l reduction for the whole kernel (lanes sharing col = query)
  l_i += __shfl_xor(l_i, 16, 64);
  l_i += __shfl_xor(l_i, 32, 64);
  {
    const float linv = 1.0f / l_i;
    float l4[4];
#pragma unroll
    for (int r = 0; r < 4; r++) l4[r] = __shfl(linv, (quad << 2) + r, 64);
#pragma unroll
    for (int d4 = 0; d4 < 4; d4++)
#pragma unroll
      for (int r = 0; r < 4; r++)
        Osh[((wv << 4) + (quad << 2) + r) * 72 + (d4 << 4) + col] = (_Float16)(accO[d4][r] * l4[r]);
  }
  __syncthreads();
  {
    const int n = nh >> 3, h = nh & 7;
    const int oi = tid >> 2, oc = (tid & 3) << 4;    // 128 rows x 64 cols
    _Float16* dst = &ctx[((size_t)n * TSEQ + q0 + oi) * DM + h * HD + oc];
    *(half8*)&dst[0] = *(const half8*)&Osh[oi * 72 + oc];
    *(half8*)&dst[8] = *(const half8*)&Osh[oi * 72 + oc + 8];
  }
}

// ---------------- output projection (f16 MFMA) + bias, f32 out ------------------
// R11 (kept): qkv-style global_load_lds double-buffered pipeline.
__global__ __launch_bounds__(256) void out_gemm_mfma(
    const _Float16* __restrict__ A, const _Float16* __restrict__ B,
    const float* __restrict__ bias, float* __restrict__ out)
{
  __shared__ __align__(16) _Float16 As0[128 * 32];
  __shared__ __align__(16) _Float16 Bs0[64 * 32];
  __shared__ __align__(16) _Float16 As1[128 * 32];
  __shared__ __align__(16) _Float16 Bs1[64 * 32];
  const int tid = threadIdx.x;
  const int wv = tid >> 6, lane = tid & 63, quad = lane >> 4, col = lane & 15;
  const int wm = wv >> 1, we = wv & 1;
  const int m0 = blockIdx.x << 7, c0 = blockIdx.y << 6;
  const int r0 = tid >> 2, p0 = tid & 3;
  const int cA0 = (p0 - (r0 >> 1)) & 3;
  const int r1 = (tid + 256) >> 2;
  const int cA1 = (p0 - (r1 >> 1)) & 3;
  const _Float16* ga0 = &A[(size_t)(m0 + r0) * DM + cA0 * 8];
  const _Float16* ga1 = &A[(size_t)(m0 + r1) * DM + cA1 * 8];
  const _Float16* gb0 = &B[(size_t)(c0 + r0) * DM + cA0 * 8];   // 64 rows, 4 phases
  floatx4 acc[4][2] = {};

#define OG_STAGE(AS, BS, K)                       \
  do {                                            \
    gl2lds16(ga0 + (K), &AS[tid * 8]);            \
    gl2lds16(ga1 + (K), &AS[(tid + 256) * 8]);    \
    gl2lds16(gb0 + (K), &BS[tid * 8]);            \
  } while (0)

#define OG_COMPUTE(AS, BS)                                                    \
  do {                                                                        \
    half8 af[4], bf[2];                                                       \
    _Pragma("unroll") for (int mt = 0; mt < 4; mt++) {                        \
      const int R = wm * 64 + mt * 16 + col;                                  \
      af[mt] = *(const half8*)&AS[R * 32 + (((quad + (R >> 1)) & 3) << 3)];   \
    }                                                                         \
    _Pragma("unroll") for (int et = 0; et < 2; et++) {                        \
      const int R = we * 32 + et * 16 + col;                                  \
      bf[et] = *(const half8*)&BS[R * 32 + (((quad + (R >> 1)) & 3) << 3)];   \
    }                                                                         \
    _Pragma("unroll") for (int mt = 0; mt < 4; mt++)                          \
      _Pragma("unroll") for (int et = 0; et < 2; et++)                        \
        acc[mt][et] =                                                         \
            __builtin_amdgcn_mfma_f32_16x16x32_f16(af[mt], bf[et], acc[mt][et], 0, 0, 0); \
  } while (0)

  OG_STAGE(As0, Bs0, 0);
  for (int k0 = 0; k0 < DM; k0 += 64) {
    __syncthreads();                    // buf0(k0) landed & visible; prev reads done
    OG_STAGE(As1, Bs1, k0 + 32);
    OG_COMPUTE(As0, Bs0);
    __syncthreads();
    if (k0 + 64 < DM) OG_STAGE(As0, Bs0, k0 + 64);
    OG_COMPUTE(As1, Bs1);
  }
#undef OG_STAGE
#undef OG_COMPUTE

  float bb[2];
#pragma unroll
  for (int et = 0; et < 2; et++) bb[et] = bias[c0 + we * 32 + et * 16 + col];
  const int mbase = m0 + wm * 64 + quad * 4;
#pragma unroll
  for (int mt = 0; mt < 4; mt++)
#pragma unroll
    for (int r = 0; r < 4; r++) {
      const int m = mbase + mt * 16 + r;
#pragma unroll
      for (int et = 0; et < 2; et++)
        out[(size_t)m * DM + c0 + we * 32 + et * 16 + col] = acc[mt][et][r] + bb[et];
    }
}

extern "C" void kernel_launch(void* const* d_in, const int* in_sizes, int n_in,
                              void* d_out, int out_size, void* d_ws, size_t ws_size,
                              hipStream_t stream) {
  const float* x    = (const float*)d_in[0];
  const float* wqkv = (const float*)d_in[1];
  const float* ow   = (const float*)d_in[2];
  const float* ob   = (const float*)d_in[3];
  char* ws = (char*)d_ws;
  _Float16* wqkvh = (_Float16*)(ws + 8650752);     //  1,572,864 B
  _Float16* owh   = (_Float16*)(ws + 10485760);    //    524,288 B
  _Float16* qbuf  = (_Float16*)(ws + 11534336);    //  8,388,608 B
  _Float16* kbuf  = (_Float16*)(ws + 20971520);    //  8,388,608 B
  _Float16* vTb   = (_Float16*)(ws + 29360128);    //  8,388,608 B
  _Float16* ctxh  = (_Float16*)(ws + 37748736);    //  8,388,608 B
  float2*   rope  = (float2*)  (ws + 46137344);    //    524,288 B -> end 46,661,632

  prep<<<640, 256, 0, stream>>>(wqkv, ow, ws);            // 163840 16B-units
  qkv_gemm_mfma<<<dim3(64, 12), 256, 0, stream>>>(x, wqkvh, rope, qbuf, kbuf, vTb);
  attn_win_mfma<<<dim3(16, 32), 512, 0, stream>>>(qbuf, kbuf, vTb, ctxh);
  out_gemm_mfma<<<dim3(64, 8), 256, 0, stream>>>(ctxh, owh, ob, (float*)d_out);
}

// Round 10
// 119.269 us; speedup vs baseline: 1.2295x; 1.2295x over previous
//
#include <hip/hip_runtime.h>
#include <math.h>

#define TSEQ 2048
#define NB 4
#define DM 512
#define NH 8
#define HD 64

typedef _Float16 half8 __attribute__((ext_vector_type(8)));
typedef _Float16 half4 __attribute__((ext_vector_type(4)));
typedef float floatx4 __attribute__((ext_vector_type(4)));

#if __has_builtin(__builtin_amdgcn_exp2f)
#define EXP2F(x) __builtin_amdgcn_exp2f(x)
#else
#define EXP2F(x) exp2f(x)
#endif

// async 16B global->LDS DMA (lane-linear LDS dest: uniform base + lane*16)
__device__ __forceinline__ void gl2lds16(const _Float16* g, _Float16* l) {
  const __attribute__((address_space(1))) unsigned int* gp =
      (const __attribute__((address_space(1))) unsigned int*)(uintptr_t)g;
  __attribute__((address_space(3))) unsigned int* lp =
      (__attribute__((address_space(3))) unsigned int*)(uintptr_t)l;
  __builtin_amdgcn_global_load_lds(gp, lp, 16, 0, 0);
}

// ws layout (bytes):
//   [0,         8388608)  xh      (f16 x)
//   [8650752,  10223616)  wqkvh   (f16 Wqkv)
//   [10485760, 11010048)  owh     (f16 out_w)
//   [11534336, 19922944)  qbuf
//   [20971520, 29360128)  kbuf
//   [29360128, 37748736)  vTb
//   [37748736, 46137344)  ctxh
//   [46137344, 46661632)  rope table (float2 [t][i])

__device__ __forceinline__ void cvt8(const float* __restrict__ src, char* __restrict__ dst,
                                     int unit_src, int unit_dst) {
  const float4 a = ((const float4*)src)[2 * unit_src];
  const float4 b = ((const float4*)src)[2 * unit_src + 1];
  half8 h;
  h[0] = (_Float16)a.x; h[1] = (_Float16)a.y; h[2] = (_Float16)a.z; h[3] = (_Float16)a.w;
  h[4] = (_Float16)b.x; h[5] = (_Float16)b.y; h[6] = (_Float16)b.z; h[7] = (_Float16)b.w;
  *(half8*)(dst + (size_t)unit_dst * 16) = h;
}

// units of 16B: xh 524288 | wqkvh 98304 | owh 32768 | rope 32768  = 688128 total
// (R15: x-cvt restored here — R13/R14 fusion regressed qkv by ~29 us)
__global__ void prep(const float* __restrict__ x, const float* __restrict__ wqkv,
                     const float* __restrict__ ow, char* __restrict__ ws) {
  const int i = blockIdx.x * 256 + threadIdx.x;   // grid exactly covers 688128
  if (i < 524288) {                         // xh
    cvt8(x, ws, i, i);
  } else if (i < 622592) {                  // wqkvh
    const int o = i - 524288;
    cvt8(wqkv, ws + 8650752, o, o);
  } else if (i < 655360) {                  // owh
    const int o = i - 622592;
    cvt8(ow, ws + 10485760, o, o);
  } else {                                  // rope table: 2 entries per 16B unit
    const int u = i - 655360;
    float4 o4;
    {
      const int id = 2 * u, t = id >> 5, fi = id & 31;
      const float invf = powf(10000.0f, -(float)(2 * fi) * (1.0f / 64.0f));
      float s, c; sincosf((float)t * invf, &s, &c);
      o4.x = c; o4.y = s;
    }
    {
      const int id = 2 * u + 1, t = id >> 5, fi = id & 31;
      const float invf = powf(10000.0f, -(float)(2 * fi) * (1.0f / 64.0f));
      float s, c; sincosf((float)t * invf, &s, &c);
      o4.z = c; o4.w = s;
    }
    ((float4*)(ws + 46137344))[u] = o4;
  }
}

// ---------------- QKV GEMM (f16 MFMA) + fused RoPE -----------------------------
// R15: 512-thread blocks (8 waves). R9 counters showed qkv latency-bound:
// Occupancy 13% (grid 768 = 3 blocks/CU x 4 waves = 12 waves/CU), MfmaUtil 7%.
// Same 128x128 tile and grid, 8 waves -> 24 waves/CU doubles TLP. Per wave:
// 32x128 output, acc[2][4], 8 MFMA/K-step. Staging = exactly 1 DMA/thread per
// array (512 x 16B = 128x32 tile). Dbuf pipeline (stage k+1 before compute k).
__global__ __launch_bounds__(512) void qkv_gemm_mfma(
    const _Float16* __restrict__ A, const _Float16* __restrict__ B,
    const float2* __restrict__ rope,
    _Float16* __restrict__ qb, _Float16* __restrict__ kb, _Float16* __restrict__ vT)
{
  __shared__ __align__(16) _Float16 As0[128 * 32];
  __shared__ __align__(16) _Float16 Bs0[128 * 32];
  __shared__ __align__(16) _Float16 As1[128 * 32];
  __shared__ __align__(16) _Float16 Bs1[128 * 32];
  const int tid = threadIdx.x;
  const int wv = tid >> 6, lane = tid & 63, quad = lane >> 4, col = lane & 15;
  const int wm = wv >> 1, we = wv & 1;               // wm 0..3 (32-row), we 0..1 (64-col)
  const int m0 = blockIdx.x << 7, c0 = blockIdx.y << 7;
  const int r0 = tid >> 2, p0 = tid & 3;             // r0 0..127
  const int cA0 = (p0 - (r0 >> 1)) & 3;
  const _Float16* ga0 = &A[(size_t)(m0 + r0) * DM + cA0 * 8];
  const _Float16* gb0 = &B[(size_t)(c0 + r0) * DM + cA0 * 8];
  floatx4 acc[2][4] = {};   // [mt][et]

#define QKV_STAGE(AS, BS, K)                      \
  do {                                            \
    gl2lds16(ga0 + (K), &AS[tid * 8]);            \
    gl2lds16(gb0 + (K), &BS[tid * 8]);            \
  } while (0)

#define QKV_COMPUTE(AS, BS)                                                   \
  do {                                                                        \
    half8 af[2], bf[4];                                                       \
    _Pragma("unroll") for (int mt = 0; mt < 2; mt++) {                        \
      const int R = wm * 32 + mt * 16 + col;                                  \
      af[mt] = *(const half8*)&AS[R * 32 + (((quad + (R >> 1)) & 3) << 3)];   \
    }                                                                         \
    _Pragma("unroll") for (int et = 0; et < 4; et++) {                        \
      const int R = we * 64 + et * 16 + col;                                  \
      bf[et] = *(const half8*)&BS[R * 32 + (((quad + (R >> 1)) & 3) << 3)];   \
    }                                                                         \
    _Pragma("unroll") for (int mt = 0; mt < 2; mt++)                          \
      _Pragma("unroll") for (int et = 0; et < 4; et++)                        \
        acc[mt][et] =                                                         \
            __builtin_amdgcn_mfma_f32_16x16x32_f16(af[mt], bf[et], acc[mt][et], 0, 0, 0); \
  } while (0)

  QKV_STAGE(As0, Bs0, 0);       // prologue: tile 0 in flight
  for (int k0 = 0; k0 < DM; k0 += 64) {
    __syncthreads();                    // buf0(k0) landed & visible; prev reads done
    QKV_STAGE(As1, Bs1, k0 + 32);       // next tile flies under compute below
    QKV_COMPUTE(As0, Bs0);
    __syncthreads();                    // buf1 landed & visible; buf0 reads done
    if (k0 + 64 < DM) QKV_STAGE(As0, Bs0, k0 + 64);
    QKV_COMPUTE(As1, Bs1);
  }
#undef QKV_STAGE
#undef QKV_COMPUTE

  const int eidx = (c0 >> 6) + we;            // 0..23, wave-uniform
  const int three = eidx >> 3, h = eidx & 7;
  const int mbase = m0 + wm * 32 + quad * 4;
  if (three == 2) {
#pragma unroll
    for (int mt = 0; mt < 2; mt++) {
      const int m = mbase + mt * 16;
      const int n = m >> 11, t = m & 2047;
#pragma unroll
      for (int et = 0; et < 4; et++) {
        const int dh = et * 16 + col;
        half4 hv;
#pragma unroll
        for (int r = 0; r < 4; r++) hv[r] = (_Float16)acc[mt][et][r];
        *(half4*)&vT[(size_t)(n * NH + h) * HD * TSEQ + (size_t)dh * TSEQ + t] = hv;
      }
    }
  } else {
    _Float16* dst = three ? kb : qb;
    // q scale = (1/8) * log2(e) so attention's exp is a bare v_exp_f32
    const float scl = three ? 1.0f : 0.125f * 1.4426950408889634f;
#pragma unroll
    for (int mt = 0; mt < 2; mt++)
#pragma unroll
      for (int r = 0; r < 4; r++) {
        const int m = mbase + mt * 16 + r;
        const int n = m >> 11, t = m & 2047;
#pragma unroll
        for (int et = 0; et < 4; et++) {
          const int i = ((et & 1) << 4) + col;
          const float2 cs = rope[t * 32 + i];
          const float v = acc[mt][et][r];
          const float v2 = acc[mt][et ^ 2][r];
          const float o = (et < 2) ? (v * cs.x - v2 * cs.y) : (v * cs.x + v2 * cs.y);
          dst[((size_t)(n * NH + h) * TSEQ + t) * HD + et * 16 + col] = (_Float16)(o * scl);
        }
      }
  }
}

// ---------------- windowed flash attention, shift-free softmax ----------------
// R12 (kept): QBLK=128, 8 waves, 6 tiles/block, wave-uniform tile+subtile skip,
// XCD swizzle, reg prefetch, 2 barriers/tile.
__global__ __launch_bounds__(512, 4) void attn_win_mfma(
    const _Float16* __restrict__ qb, const _Float16* __restrict__ kb,
    const _Float16* __restrict__ vT, _Float16* __restrict__ ctx)
{
  __shared__ __align__(16) char smem[55296];
  _Float16* Ks = (_Float16*)smem;              // [64][72] j-major
  _Float16* Vt = (_Float16*)(smem + 9216);     // [64][72] d-major (from vT global)
  _Float16* Ps = (_Float16*)(smem + 18432);    // [128][72] i-major (wave-private rows)
  _Float16* Osh = (_Float16*)(smem + 36864);   // [128][72]

  const int tid = threadIdx.x;
  const int wv = tid >> 6;                     // 0..7
  const int lane = tid & 63;
  const int quad = lane >> 4;
  const int col = lane & 15;
  // XCD swizzle: lin%8 = XCD -> 64 contiguous sl per XCD = 4 batch-heads
  const int lin = (blockIdx.y << 4) | blockIdx.x;          // 0..511
  const int sl  = ((lin & 7) << 6) | (lin >> 3);
  const int nh = sl >> 4;
  const int q0 = (sl & 15) << 7;
  const _Float16* qp = qb + (size_t)nh * TSEQ * HD;
  const _Float16* kp = kb + (size_t)nh * TSEQ * HD;
  const _Float16* vp = vT + (size_t)nh * HD * TSEQ;

  const int i_row = (wv << 4) + col;           // 0..127
  const int ig = q0 + i_row;
  const half8 qf0 = *(const half8*)&qp[(size_t)ig * HD + (quad << 3)];
  const half8 qf1 = *(const half8*)&qp[(size_t)ig * HD + 32 + (quad << 3)];

  float l_i = 0.0f;          // per-lane partial sum of p
  floatx4 accO[4] = {};

  const int kt0 = max(0, q0 - 127) >> 6;
  const int kt1 = min(TSEQ - 1, q0 + 255) >> 6;
  // staging: 512 threads cover one 64x64 f16 tile at 16B/thread
  const int kr = tid >> 3, kc = (tid & 7) << 3;      // row 0..63, col-chunk 0..56
  const _Float16* kpr = kp + (size_t)kr * HD + kc;   // + j0*HD selects K tile
  const _Float16* vpr = vp + (size_t)kr * TSEQ + kc; // + j0 selects V^T tile
  const int iw0 = q0 + (wv << 4);                    // wave's first query

  // prologue: load first tile into registers
  half8 ck = *(const half8*)(kpr + (size_t)(kt0 << 6) * HD);
  half8 cv = *(const half8*)(vpr + (kt0 << 6));

  for (int kt = kt0; kt <= kt1; kt++) {
    const int j0 = kt << 6;
    __syncthreads();   // previous iteration's LDS reads complete
    *(half8*)&Ks[kr * 72 + kc] = ck;
    *(half8*)&Vt[kr * 72 + kc] = cv;
    __syncthreads();   // staging visible

    // prefetch NEXT tile into registers; latency hides under compute below.
    {
      const int jn = (kt < kt1) ? (j0 + 64) : j0;
      ck = *(const half8*)(kpr + (size_t)jn * HD);
      cv = *(const half8*)(vpr + jn);
    }

    // wave-uniform whole-tile skip: tile [j0, j0+63] intersects wave window
    // [iw0-127, iw0+143] iff j0 in [iw0-190, iw0+143]
    if ((unsigned)(j0 - iw0 + 190) >= 334u) continue;

    // live(js): subtile [jlo, jlo+15] intersects [iw0-127, iw0+143]
    // <=> (unsigned)(jlo - iw0 + 142) < 286
    // S^T[j][i]: A = K rows, B = Q^T. C-layout: row=j_local, col=i(=our query)
    floatx4 S[4];
#pragma unroll
    for (int js = 0; js < 4; js++) {
      const int jlo = j0 + (js << 4);
      if ((unsigned)(jlo - iw0 + 142) < 286u) {
        const half8 a0 = *(const half8*)&Ks[((js << 4) + col) * 72 + (quad << 3)];
        const half8 a1 = *(const half8*)&Ks[((js << 4) + col) * 72 + 32 + (quad << 3)];
        floatx4 c = {0.f, 0.f, 0.f, 0.f};
        c = __builtin_amdgcn_mfma_f32_16x16x32_f16(a0, qf0, c, 0, 0, 0);
        c = __builtin_amdgcn_mfma_f32_16x16x32_f16(a1, qf1, c, 0, 0, 0);
        S[js] = c;
      }
    }
    // mask -> p = exp2(s) (q carries log2e/8); masked p = 0. No max, no rescale.
    // window test: j in [ig-127, ig+128]  <=>  (unsigned)(j - ig + 127) < 256
    const int relb = j0 - ig + 127 + (quad << 2);
#pragma unroll
    for (int js = 0; js < 4; js++) {
      const int jlo = j0 + (js << 4);
      if ((unsigned)(jlo - iw0 + 142) < 286u) {
        half4 ph;
#pragma unroll
        for (int r = 0; r < 4; r++) {
          const bool valid = (unsigned)(relb + (js << 4) + r) < 256u;
          const float p = valid ? EXP2F(S[js][r]) : 0.0f;
          l_i += p;
          ph[r] = (_Float16)p;
        }
        *(half4*)&Ps[i_row * 72 + (js << 4) + (quad << 2)] = ph;
      } else {
        const half4 zz = {(_Float16)0.f, (_Float16)0.f, (_Float16)0.f, (_Float16)0.f};
        *(half4*)&Ps[i_row * 72 + (js << 4) + (quad << 2)] = zz;
      }
    }
    // PV directly: Ps rows are wave-private; same-wave LDS ordering suffices.
    const half8 pa0 = *(const half8*)&Ps[i_row * 72 + (quad << 3)];
    const half8 pa1 = *(const half8*)&Ps[i_row * 72 + 32 + (quad << 3)];
#pragma unroll
    for (int d4 = 0; d4 < 4; d4++) {
      const half8 vb0 = *(const half8*)&Vt[((d4 << 4) + col) * 72 + (quad << 3)];
      const half8 vb1 = *(const half8*)&Vt[((d4 << 4) + col) * 72 + 32 + (quad << 3)];
      accO[d4] = __builtin_amdgcn_mfma_f32_16x16x32_f16(pa0, vb0, accO[d4], 0, 0, 0);
      accO[d4] = __builtin_amdgcn_mfma_f32_16x16x32_f16(pa1, vb1, accO[d4], 0, 0, 0);
    }
  }
  // one cross-lane l reduction for the whole kernel (lanes sharing col = query)
  l_i += __shfl_xor(l_i, 16, 64);
  l_i += __shfl_xor(l_i, 32, 64);
  {
    const float linv = 1.0f / l_i;
    float l4[4];
#pragma unroll
    for (int r = 0; r < 4; r++) l4[r] = __shfl(linv, (quad << 2) + r, 64);
#pragma unroll
    for (int d4 = 0; d4 < 4; d4++)
#pragma unroll
      for (int r = 0; r < 4; r++)
        Osh[((wv << 4) + (quad << 2) + r) * 72 + (d4 << 4) + col] = (_Float16)(accO[d4][r] * l4[r]);
  }
  __syncthreads();
  {
    const int n = nh >> 3, h = nh & 7;
    const int oi = tid >> 2, oc = (tid & 3) << 4;    // 128 rows x 64 cols
    _Float16* dst = &ctx[((size_t)n * TSEQ + q0 + oi) * DM + h * HD + oc];
    *(half8*)&dst[0] = *(const half8*)&Osh[oi * 72 + oc];
    *(half8*)&dst[8] = *(const half8*)&Osh[oi * 72 + oc + 8];
  }
}

// ---------------- output projection (f16 MFMA) + bias, f32 out ------------------
// R11 (kept): qkv-style global_load_lds double-buffered pipeline.
__global__ __launch_bounds__(256) void out_gemm_mfma(
    const _Float16* __restrict__ A, const _Float16* __restrict__ B,
    const float* __restrict__ bias, float* __restrict__ out)
{
  __shared__ __align__(16) _Float16 As0[128 * 32];
  __shared__ __align__(16) _Float16 Bs0[64 * 32];
  __shared__ __align__(16) _Float16 As1[128 * 32];
  __shared__ __align__(16) _Float16 Bs1[64 * 32];
  const int tid = threadIdx.x;
  const int wv = tid >> 6, lane = tid & 63, quad = lane >> 4, col = lane & 15;
  const int wm = wv >> 1, we = wv & 1;
  const int m0 = blockIdx.x << 7, c0 = blockIdx.y << 6;
  const int r0 = tid >> 2, p0 = tid & 3;
  const int cA0 = (p0 - (r0 >> 1)) & 3;
  const int r1 = (tid + 256) >> 2;
  const int cA1 = (p0 - (r1 >> 1)) & 3;
  const _Float16* ga0 = &A[(size_t)(m0 + r0) * DM + cA0 * 8];
  const _Float16* ga1 = &A[(size_t)(m0 + r1) * DM + cA1 * 8];
  const _Float16* gb0 = &B[(size_t)(c0 + r0) * DM + cA0 * 8];   // 64 rows, 4 phases
  floatx4 acc[4][2] = {};

#define OG_STAGE(AS, BS, K)                       \
  do {                                            \
    gl2lds16(ga0 + (K), &AS[tid * 8]);            \
    gl2lds16(ga1 + (K), &AS[(tid + 256) * 8]);    \
    gl2lds16(gb0 + (K), &BS[tid * 8]);            \
  } while (0)

#define OG_COMPUTE(AS, BS)                                                    \
  do {                                                                        \
    half8 af[4], bf[2];                                                       \
    _Pragma("unroll") for (int mt = 0; mt < 4; mt++) {                        \
      const int R = wm * 64 + mt * 16 + col;                                  \
      af[mt] = *(const half8*)&AS[R * 32 + (((quad + (R >> 1)) & 3) << 3)];   \
    }                                                                         \
    _Pragma("unroll") for (int et = 0; et < 2; et++) {                        \
      const int R = we * 32 + et * 16 + col;                                  \
      bf[et] = *(const half8*)&BS[R * 32 + (((quad + (R >> 1)) & 3) << 3)];   \
    }                                                                         \
    _Pragma("unroll") for (int mt = 0; mt < 4; mt++)                          \
      _Pragma("unroll") for (int et = 0; et < 2; et++)                        \
        acc[mt][et] =                                                         \
            __builtin_amdgcn_mfma_f32_16x16x32_f16(af[mt], bf[et], acc[mt][et], 0, 0, 0); \
  } while (0)

  OG_STAGE(As0, Bs0, 0);
  for (int k0 = 0; k0 < DM; k0 += 64) {
    __syncthreads();                    // buf0(k0) landed & visible; prev reads done
    OG_STAGE(As1, Bs1, k0 + 32);
    OG_COMPUTE(As0, Bs0);
    __syncthreads();
    if (k0 + 64 < DM) OG_STAGE(As0, Bs0, k0 + 64);
    OG_COMPUTE(As1, Bs1);
  }
#undef OG_STAGE
#undef OG_COMPUTE

  float bb[2];
#pragma unroll
  for (int et = 0; et < 2; et++) bb[et] = bias[c0 + we * 32 + et * 16 + col];
  const int mbase = m0 + wm * 64 + quad * 4;
#pragma unroll
  for (int mt = 0; mt < 4; mt++)
#pragma unroll
    for (int r = 0; r < 4; r++) {
      const int m = mbase + mt * 16 + r;
#pragma unroll
      for (int et = 0; et < 2; et++)
        out[(size_t)m * DM + c0 + we * 32 + et * 16 + col] = acc[mt][et][r] + bb[et];
    }
}

extern "C" void kernel_launch(void* const* d_in, const int* in_sizes, int n_in,
                              void* d_out, int out_size, void* d_ws, size_t ws_size,
                              hipStream_t stream) {
  const float* x    = (const float*)d_in[0];
  const float* wqkv = (const float*)d_in[1];
  const float* ow   = (const float*)d_in[2];
  const float* ob   = (const float*)d_in[3];
  char* ws = (char*)d_ws;
  _Float16* xh    = (_Float16*)(ws);               //  8,388,608 B
  _Float16* wqkvh = (_Float16*)(ws + 8650752);     //  1,572,864 B
  _Float16* owh   = (_Float16*)(ws + 10485760);    //    524,288 B
  _Float16* qbuf  = (_Float16*)(ws + 11534336);    //  8,388,608 B
  _Float16* kbuf  = (_Float16*)(ws + 20971520);    //  8,388,608 B
  _Float16* vTb   = (_Float16*)(ws + 29360128);    //  8,388,608 B
  _Float16* ctxh  = (_Float16*)(ws + 37748736);    //  8,388,608 B
  float2*   rope  = (float2*)  (ws + 46137344);    //    524,288 B -> end 46,661,632

  prep<<<2688, 256, 0, stream>>>(x, wqkv, ow, ws);        // 688128 16B-units
  qkv_gemm_mfma<<<dim3(64, 12), 512, 0, stream>>>(xh, wqkvh, rope, qbuf, kbuf, vTb);
  attn_win_mfma<<<dim3(16, 32), 512, 0, stream>>>(qbuf, kbuf, vTb, ctxh);
  out_gemm_mfma<<<dim3(64, 8), 256, 0, stream>>>(ctxh, owh, ob, (float*)d_out);
}

// Round 11
// 118.128 us; speedup vs baseline: 1.2413x; 1.0097x over previous
//
#include <hip/hip_runtime.h>
#include <math.h>

#define TSEQ 2048
#define NB 4
#define DM 512
#define NH 8
#define HD 64

typedef _Float16 half8 __attribute__((ext_vector_type(8)));
typedef _Float16 half4 __attribute__((ext_vector_type(4)));
typedef float floatx4 __attribute__((ext_vector_type(4)));

#if __has_builtin(__builtin_amdgcn_exp2f)
#define EXP2F(x) __builtin_amdgcn_exp2f(x)
#else
#define EXP2F(x) exp2f(x)
#endif

// async 16B global->LDS DMA (lane-linear LDS dest: uniform base + lane*16)
__device__ __forceinline__ void gl2lds16(const _Float16* g, _Float16* l) {
  const __attribute__((address_space(1))) unsigned int* gp =
      (const __attribute__((address_space(1))) unsigned int*)(uintptr_t)g;
  __attribute__((address_space(3))) unsigned int* lp =
      (__attribute__((address_space(3))) unsigned int*)(uintptr_t)l;
  __builtin_amdgcn_global_load_lds(gp, lp, 16, 0, 0);
}

// ws layout (bytes):
//   [0,         8388608)  xh      (f16 x)
//   [8650752,  10223616)  wqkvh   (f16 Wqkv)
//   [10485760, 11010048)  owh     (f16 out_w)
//   [11534336, 19922944)  qbuf
//   [20971520, 29360128)  kbuf
//   [29360128, 37748736)  vTb
//   [37748736, 46137344)  ctxh
//   [46137344, 46661632)  rope table (float2 [t][i])

__device__ __forceinline__ void cvt8(const float* __restrict__ src, char* __restrict__ dst,
                                     int unit_src, int unit_dst) {
  const float4 a = ((const float4*)src)[2 * unit_src];
  const float4 b = ((const float4*)src)[2 * unit_src + 1];
  half8 h;
  h[0] = (_Float16)a.x; h[1] = (_Float16)a.y; h[2] = (_Float16)a.z; h[3] = (_Float16)a.w;
  h[4] = (_Float16)b.x; h[5] = (_Float16)b.y; h[6] = (_Float16)b.z; h[7] = (_Float16)b.w;
  *(half8*)(dst + (size_t)unit_dst * 16) = h;
}

// units of 16B: xh 524288 | wqkvh 98304 | owh 32768 | rope 32768  = 688128 total
__global__ void prep(const float* __restrict__ x, const float* __restrict__ wqkv,
                     const float* __restrict__ ow, char* __restrict__ ws) {
  const int i = blockIdx.x * 256 + threadIdx.x;   // grid exactly covers 688128
  if (i < 524288) {                         // xh
    cvt8(x, ws, i, i);
  } else if (i < 622592) {                  // wqkvh
    const int o = i - 524288;
    cvt8(wqkv, ws + 8650752, o, o);
  } else if (i < 655360) {                  // owh
    const int o = i - 622592;
    cvt8(ow, ws + 10485760, o, o);
  } else {                                  // rope table: 2 entries per 16B unit
    const int u = i - 655360;
    float4 o4;
    {
      const int id = 2 * u, t = id >> 5, fi = id & 31;
      const float invf = powf(10000.0f, -(float)(2 * fi) * (1.0f / 64.0f));
      float s, c; sincosf((float)t * invf, &s, &c);
      o4.x = c; o4.y = s;
    }
    {
      const int id = 2 * u + 1, t = id >> 5, fi = id & 31;
      const float invf = powf(10000.0f, -(float)(2 * fi) * (1.0f / 64.0f));
      float s, c; sincosf((float)t * invf, &s, &c);
      o4.z = c; o4.w = s;
    }
    ((float4*)(ws + 46137344))[u] = o4;
  }
}

// ---------------- QKV GEMM (f16 MFMA) + fused RoPE -----------------------------
// R15 (kept): 512-thread blocks (8 waves) -> 24 waves/CU. Per wave: 32x128
// output, acc[2][4]. Staging = 1 DMA/thread per array. Dbuf pipeline.
__global__ __launch_bounds__(512) void qkv_gemm_mfma(
    const _Float16* __restrict__ A, const _Float16* __restrict__ B,
    const float2* __restrict__ rope,
    _Float16* __restrict__ qb, _Float16* __restrict__ kb, _Float16* __restrict__ vT)
{
  __shared__ __align__(16) _Float16 As0[128 * 32];
  __shared__ __align__(16) _Float16 Bs0[128 * 32];
  __shared__ __align__(16) _Float16 As1[128 * 32];
  __shared__ __align__(16) _Float16 Bs1[128 * 32];
  const int tid = threadIdx.x;
  const int wv = tid >> 6, lane = tid & 63, quad = lane >> 4, col = lane & 15;
  const int wm = wv >> 1, we = wv & 1;               // wm 0..3 (32-row), we 0..1 (64-col)
  const int m0 = blockIdx.x << 7, c0 = blockIdx.y << 7;
  const int r0 = tid >> 2, p0 = tid & 3;             // r0 0..127
  const int cA0 = (p0 - (r0 >> 1)) & 3;
  const _Float16* ga0 = &A[(size_t)(m0 + r0) * DM + cA0 * 8];
  const _Float16* gb0 = &B[(size_t)(c0 + r0) * DM + cA0 * 8];
  floatx4 acc[2][4] = {};   // [mt][et]

#define QKV_STAGE(AS, BS, K)                      \
  do {                                            \
    gl2lds16(ga0 + (K), &AS[tid * 8]);            \
    gl2lds16(gb0 + (K), &BS[tid * 8]);            \
  } while (0)

#define QKV_COMPUTE(AS, BS)                                                   \
  do {                                                                        \
    half8 af[2], bf[4];                                                       \
    _Pragma("unroll") for (int mt = 0; mt < 2; mt++) {                        \
      const int R = wm * 32 + mt * 16 + col;                                  \
      af[mt] = *(const half8*)&AS[R * 32 + (((quad + (R >> 1)) & 3) << 3)];   \
    }                                                                         \
    _Pragma("unroll") for (int et = 0; et < 4; et++) {                        \
      const int R = we * 64 + et * 16 + col;                                  \
      bf[et] = *(const half8*)&BS[R * 32 + (((quad + (R >> 1)) & 3) << 3)];   \
    }                                                                         \
    _Pragma("unroll") for (int mt = 0; mt < 2; mt++)                          \
      _Pragma("unroll") for (int et = 0; et < 4; et++)                        \
        acc[mt][et] =                                                         \
            __builtin_amdgcn_mfma_f32_16x16x32_f16(af[mt], bf[et], acc[mt][et], 0, 0, 0); \
  } while (0)

  QKV_STAGE(As0, Bs0, 0);       // prologue: tile 0 in flight
  for (int k0 = 0; k0 < DM; k0 += 64) {
    __syncthreads();                    // buf0(k0) landed & visible; prev reads done
    QKV_STAGE(As1, Bs1, k0 + 32);       // next tile flies under compute below
    QKV_COMPUTE(As0, Bs0);
    __syncthreads();                    // buf1 landed & visible; buf0 reads done
    if (k0 + 64 < DM) QKV_STAGE(As0, Bs0, k0 + 64);
    QKV_COMPUTE(As1, Bs1);
  }
#undef QKV_STAGE
#undef QKV_COMPUTE

  const int eidx = (c0 >> 6) + we;            // 0..23, wave-uniform
  const int three = eidx >> 3, h = eidx & 7;
  const int mbase = m0 + wm * 32 + quad * 4;
  if (three == 2) {
#pragma unroll
    for (int mt = 0; mt < 2; mt++) {
      const int m = mbase + mt * 16;
      const int n = m >> 11, t = m & 2047;
#pragma unroll
      for (int et = 0; et < 4; et++) {
        const int dh = et * 16 + col;
        half4 hv;
#pragma unroll
        for (int r = 0; r < 4; r++) hv[r] = (_Float16)acc[mt][et][r];
        *(half4*)&vT[(size_t)(n * NH + h) * HD * TSEQ + (size_t)dh * TSEQ + t] = hv;
      }
    }
  } else {
    _Float16* dst = three ? kb : qb;
    // q scale = (1/8) * log2(e) so attention's exp is a bare v_exp_f32
    const float scl = three ? 1.0f : 0.125f * 1.4426950408889634f;
#pragma unroll
    for (int mt = 0; mt < 2; mt++)
#pragma unroll
      for (int r = 0; r < 4; r++) {
        const int m = mbase + mt * 16 + r;
        const int n = m >> 11, t = m & 2047;
#pragma unroll
        for (int et = 0; et < 4; et++) {
          const int i = ((et & 1) << 4) + col;
          const float2 cs = rope[t * 32 + i];
          const float v = acc[mt][et][r];
          const float v2 = acc[mt][et ^ 2][r];
          const float o = (et < 2) ? (v * cs.x - v2 * cs.y) : (v * cs.x + v2 * cs.y);
          dst[((size_t)(n * NH + h) * TSEQ + t) * HD + et * 16 + col] = (_Float16)(o * scl);
        }
      }
  }
}

// ---------------- windowed flash attention, shift-free softmax ----------------
// R12 (kept): QBLK=128, 8 waves, 6 tiles/block, wave-uniform tile+subtile skip,
// XCD swizzle, reg prefetch, 2 barriers/tile.
__global__ __launch_bounds__(512, 4) void attn_win_mfma(
    const _Float16* __restrict__ qb, const _Float16* __restrict__ kb,
    const _Float16* __restrict__ vT, _Float16* __restrict__ ctx)
{
  __shared__ __align__(16) char smem[55296];
  _Float16* Ks = (_Float16*)smem;              // [64][72] j-major
  _Float16* Vt = (_Float16*)(smem + 9216);     // [64][72] d-major (from vT global)
  _Float16* Ps = (_Float16*)(smem + 18432);    // [128][72] i-major (wave-private rows)
  _Float16* Osh = (_Float16*)(smem + 36864);   // [128][72]

  const int tid = threadIdx.x;
  const int wv = tid >> 6;                     // 0..7
  const int lane = tid & 63;
  const int quad = lane >> 4;
  const int col = lane & 15;
  // XCD swizzle: lin%8 = XCD -> 64 contiguous sl per XCD = 4 batch-heads
  const int lin = (blockIdx.y << 4) | blockIdx.x;          // 0..511
  const int sl  = ((lin & 7) << 6) | (lin >> 3);
  const int nh = sl >> 4;
  const int q0 = (sl & 15) << 7;
  const _Float16* qp = qb + (size_t)nh * TSEQ * HD;
  const _Float16* kp = kb + (size_t)nh * TSEQ * HD;
  const _Float16* vp = vT + (size_t)nh * HD * TSEQ;

  const int i_row = (wv << 4) + col;           // 0..127
  const int ig = q0 + i_row;
  const half8 qf0 = *(const half8*)&qp[(size_t)ig * HD + (quad << 3)];
  const half8 qf1 = *(const half8*)&qp[(size_t)ig * HD + 32 + (quad << 3)];

  float l_i = 0.0f;          // per-lane partial sum of p
  floatx4 accO[4] = {};

  const int kt0 = max(0, q0 - 127) >> 6;
  const int kt1 = min(TSEQ - 1, q0 + 255) >> 6;
  // staging: 512 threads cover one 64x64 f16 tile at 16B/thread
  const int kr = tid >> 3, kc = (tid & 7) << 3;      // row 0..63, col-chunk 0..56
  const _Float16* kpr = kp + (size_t)kr * HD + kc;   // + j0*HD selects K tile
  const _Float16* vpr = vp + (size_t)kr * TSEQ + kc; // + j0 selects V^T tile
  const int iw0 = q0 + (wv << 4);                    // wave's first query

  // prologue: load first tile into registers
  half8 ck = *(const half8*)(kpr + (size_t)(kt0 << 6) * HD);
  half8 cv = *(const half8*)(vpr + (kt0 << 6));

  for (int kt = kt0; kt <= kt1; kt++) {
    const int j0 = kt << 6;
    __syncthreads();   // previous iteration's LDS reads complete
    *(half8*)&Ks[kr * 72 + kc] = ck;
    *(half8*)&Vt[kr * 72 + kc] = cv;
    __syncthreads();   // staging visible

    // prefetch NEXT tile into registers; latency hides under compute below.
    {
      const int jn = (kt < kt1) ? (j0 + 64) : j0;
      ck = *(const half8*)(kpr + (size_t)jn * HD);
      cv = *(const half8*)(vpr + jn);
    }

    // wave-uniform whole-tile skip: tile [j0, j0+63] intersects wave window
    // [iw0-127, iw0+143] iff j0 in [iw0-190, iw0+143]
    if ((unsigned)(j0 - iw0 + 190) >= 334u) continue;

    // live(js): subtile [jlo, jlo+15] intersects [iw0-127, iw0+143]
    // <=> (unsigned)(jlo - iw0 + 142) < 286
    // S^T[j][i]: A = K rows, B = Q^T. C-layout: row=j_local, col=i(=our query)
    floatx4 S[4];
#pragma unroll
    for (int js = 0; js < 4; js++) {
      const int jlo = j0 + (js << 4);
      if ((unsigned)(jlo - iw0 + 142) < 286u) {
        const half8 a0 = *(const half8*)&Ks[((js << 4) + col) * 72 + (quad << 3)];
        const half8 a1 = *(const half8*)&Ks[((js << 4) + col) * 72 + 32 + (quad << 3)];
        floatx4 c = {0.f, 0.f, 0.f, 0.f};
        c = __builtin_amdgcn_mfma_f32_16x16x32_f16(a0, qf0, c, 0, 0, 0);
        c = __builtin_amdgcn_mfma_f32_16x16x32_f16(a1, qf1, c, 0, 0, 0);
        S[js] = c;
      }
    }
    // mask -> p = exp2(s) (q carries log2e/8); masked p = 0. No max, no rescale.
    // window test: j in [ig-127, ig+128]  <=>  (unsigned)(j - ig + 127) < 256
    const int relb = j0 - ig + 127 + (quad << 2);
#pragma unroll
    for (int js = 0; js < 4; js++) {
      const int jlo = j0 + (js << 4);
      if ((unsigned)(jlo - iw0 + 142) < 286u) {
        half4 ph;
#pragma unroll
        for (int r = 0; r < 4; r++) {
          const bool valid = (unsigned)(relb + (js << 4) + r) < 256u;
          const float p = valid ? EXP2F(S[js][r]) : 0.0f;
          l_i += p;
          ph[r] = (_Float16)p;
        }
        *(half4*)&Ps[i_row * 72 + (js << 4) + (quad << 2)] = ph;
      } else {
        const half4 zz = {(_Float16)0.f, (_Float16)0.f, (_Float16)0.f, (_Float16)0.f};
        *(half4*)&Ps[i_row * 72 + (js << 4) + (quad << 2)] = zz;
      }
    }
    // PV directly: Ps rows are wave-private; same-wave LDS ordering suffices.
    const half8 pa0 = *(const half8*)&Ps[i_row * 72 + (quad << 3)];
    const half8 pa1 = *(const half8*)&Ps[i_row * 72 + 32 + (quad << 3)];
#pragma unroll
    for (int d4 = 0; d4 < 4; d4++) {
      const half8 vb0 = *(const half8*)&Vt[((d4 << 4) + col) * 72 + (quad << 3)];
      const half8 vb1 = *(const half8*)&Vt[((d4 << 4) + col) * 72 + 32 + (quad << 3)];
      accO[d4] = __builtin_amdgcn_mfma_f32_16x16x32_f16(pa0, vb0, accO[d4], 0, 0, 0);
      accO[d4] = __builtin_amdgcn_mfma_f32_16x16x32_f16(pa1, vb1, accO[d4], 0, 0, 0);
    }
  }
  // one cross-lane l reduction for the whole kernel (lanes sharing col = query)
  l_i += __shfl_xor(l_i, 16, 64);
  l_i += __shfl_xor(l_i, 32, 64);
  {
    const float linv = 1.0f / l_i;
    float l4[4];
#pragma unroll
    for (int r = 0; r < 4; r++) l4[r] = __shfl(linv, (quad << 2) + r, 64);
#pragma unroll
    for (int d4 = 0; d4 < 4; d4++)
#pragma unroll
      for (int r = 0; r < 4; r++)
        Osh[((wv << 4) + (quad << 2) + r) * 72 + (d4 << 4) + col] = (_Float16)(accO[d4][r] * l4[r]);
  }
  __syncthreads();
  {
    const int n = nh >> 3, h = nh & 7;
    const int oi = tid >> 2, oc = (tid & 3) << 4;    // 128 rows x 64 cols
    _Float16* dst = &ctx[((size_t)n * TSEQ + q0 + oi) * DM + h * HD + oc];
    *(half8*)&dst[0] = *(const half8*)&Osh[oi * 72 + oc];
    *(half8*)&dst[8] = *(const half8*)&Osh[oi * 72 + oc + 8];
  }
}

// ---------------- output projection (f16 MFMA) + bias, f32 out ------------------
// R16: 512-thread blocks (8 waves). Old version ran 2 blocks/CU x 4 waves =
// 8 waves/CU (2/SIMD) -- the same under-occupancy that R9's counters showed for
// qkv (Occ 13%, MfmaUtil 7%). Same 128x64 tile, 8 waves each owning a 32x32
// sub-tile (acc[2][2]) -> 16 waves/CU. Staging: A = 1 DMA/thread (128x32),
// B = 1 DMA for tid<256 (64x32). Dbuf pipeline unchanged.
__global__ __launch_bounds__(512) void out_gemm_mfma(
    const _Float16* __restrict__ A, const _Float16* __restrict__ B,
    const float* __restrict__ bias, float* __restrict__ out)
{
  __shared__ __align__(16) _Float16 As0[128 * 32];
  __shared__ __align__(16) _Float16 Bs0[64 * 32];
  __shared__ __align__(16) _Float16 As1[128 * 32];
  __shared__ __align__(16) _Float16 Bs1[64 * 32];
  const int tid = threadIdx.x;
  const int wv = tid >> 6, lane = tid & 63, quad = lane >> 4, col = lane & 15;
  const int wm = wv >> 1, we = wv & 1;               // wm 0..3 (32-row), we 0..1 (32-col)
  const int m0 = blockIdx.x << 7, c0 = blockIdx.y << 6;
  const int r0 = tid >> 2, p0 = tid & 3;             // A: r0 0..127
  const int cA0 = (p0 - (r0 >> 1)) & 3;
  const _Float16* ga0 = &A[(size_t)(m0 + r0) * DM + cA0 * 8];
  const _Float16* gb0 = &B[(size_t)(c0 + r0) * DM + cA0 * 8];   // valid for tid<256 (r0<64)
  floatx4 acc[2][2] = {};

#define OG_STAGE(AS, BS, K)                       \
  do {                                            \
    gl2lds16(ga0 + (K), &AS[tid * 8]);            \
    if (tid < 256) gl2lds16(gb0 + (K), &BS[tid * 8]); \
  } while (0)

#define OG_COMPUTE(AS, BS)                                                    \
  do {                                                                        \
    half8 af[2], bf[2];                                                       \
    _Pragma("unroll") for (int mt = 0; mt < 2; mt++) {                        \
      const int R = wm * 32 + mt * 16 + col;                                  \
      af[mt] = *(const half8*)&AS[R * 32 + (((quad + (R >> 1)) & 3) << 3)];   \
    }                                                                         \
    _Pragma("unroll") for (int et = 0; et < 2; et++) {                        \
      const int R = we * 32 + et * 16 + col;                                  \
      bf[et] = *(const half8*)&BS[R * 32 + (((quad + (R >> 1)) & 3) << 3)];   \
    }                                                                         \
    _Pragma("unroll") for (int mt = 0; mt < 2; mt++)                          \
      _Pragma("unroll") for (int et = 0; et < 2; et++)                        \
        acc[mt][et] =                                                         \
            __builtin_amdgcn_mfma_f32_16x16x32_f16(af[mt], bf[et], acc[mt][et], 0, 0, 0); \
  } while (0)

  OG_STAGE(As0, Bs0, 0);
  for (int k0 = 0; k0 < DM; k0 += 64) {
    __syncthreads();                    // buf0(k0) landed & visible; prev reads done
    OG_STAGE(As1, Bs1, k0 + 32);
    OG_COMPUTE(As0, Bs0);
    __syncthreads();
    if (k0 + 64 < DM) OG_STAGE(As0, Bs0, k0 + 64);
    OG_COMPUTE(As1, Bs1);
  }
#undef OG_STAGE
#undef OG_COMPUTE

  float bb[2];
#pragma unroll
  for (int et = 0; et < 2; et++) bb[et] = bias[c0 + we * 32 + et * 16 + col];
  const int mbase = m0 + wm * 32 + quad * 4;
#pragma unroll
  for (int mt = 0; mt < 2; mt++)
#pragma unroll
    for (int r = 0; r < 4; r++) {
      const int m = mbase + mt * 16 + r;
#pragma unroll
      for (int et = 0; et < 2; et++)
        out[(size_t)m * DM + c0 + we * 32 + et * 16 + col] = acc[mt][et][r] + bb[et];
    }
}

extern "C" void kernel_launch(void* const* d_in, const int* in_sizes, int n_in,
                              void* d_out, int out_size, void* d_ws, size_t ws_size,
                              hipStream_t stream) {
  const float* x    = (const float*)d_in[0];
  const float* wqkv = (const float*)d_in[1];
  const float* ow   = (const float*)d_in[2];
  const float* ob   = (const float*)d_in[3];
  char* ws = (char*)d_ws;
  _Float16* xh    = (_Float16*)(ws);               //  8,388,608 B
  _Float16* wqkvh = (_Float16*)(ws + 8650752);     //  1,572,864 B
  _Float16* owh   = (_Float16*)(ws + 10485760);    //    524,288 B
  _Float16* qbuf  = (_Float16*)(ws + 11534336);    //  8,388,608 B
  _Float16* kbuf  = (_Float16*)(ws + 20971520);    //  8,388,608 B
  _Float16* vTb   = (_Float16*)(ws + 29360128);    //  8,388,608 B
  _Float16* ctxh  = (_Float16*)(ws + 37748736);    //  8,388,608 B
  float2*   rope  = (float2*)  (ws + 46137344);    //    524,288 B -> end 46,661,632

  prep<<<2688, 256, 0, stream>>>(x, wqkv, ow, ws);        // 688128 16B-units
  qkv_gemm_mfma<<<dim3(64, 12), 512, 0, stream>>>(xh, wqkvh, rope, qbuf, kbuf, vTb);
  attn_win_mfma<<<dim3(16, 32), 512, 0, stream>>>(qbuf, kbuf, vTb, ctxh);
  out_gemm_mfma<<<dim3(64, 8), 512, 0, stream>>>(ctxh, owh, ob, (float*)d_out);
}

// Round 12
// 118.112 us; speedup vs baseline: 1.2415x; 1.0001x over previous
//
#include <hip/hip_runtime.h>
#include <math.h>

#define TSEQ 2048
#define NB 4
#define DM 512
#define NH 8
#define HD 64

typedef _Float16 half8 __attribute__((ext_vector_type(8)));
typedef _Float16 half4 __attribute__((ext_vector_type(4)));
typedef float floatx4 __attribute__((ext_vector_type(4)));

#if __has_builtin(__builtin_amdgcn_exp2f)
#define EXP2F(x) __builtin_amdgcn_exp2f(x)
#else
#define EXP2F(x) exp2f(x)
#endif

// async 16B global->LDS DMA (lane-linear LDS dest: uniform base + lane*16)
__device__ __forceinline__ void gl2lds16(const _Float16* g, _Float16* l) {
  const __attribute__((address_space(1))) unsigned int* gp =
      (const __attribute__((address_space(1))) unsigned int*)(uintptr_t)g;
  __attribute__((address_space(3))) unsigned int* lp =
      (__attribute__((address_space(3))) unsigned int*)(uintptr_t)l;
  __builtin_amdgcn_global_load_lds(gp, lp, 16, 0, 0);
}

// ws layout (bytes):
//   [0,         8388608)  xh      (f16 x)
//   [8650752,  10223616)  wqkvh   (f16 Wqkv)
//   [10485760, 11010048)  owh     (f16 out_w)
//   [11534336, 19922944)  qbuf
//   [20971520, 29360128)  kbuf
//   [29360128, 37748736)  vTb
//   [37748736, 46137344)  ctxh
//   [46137344, 46661632)  rope table (float2 [t][i])

__device__ __forceinline__ void cvt8(const float* __restrict__ src, char* __restrict__ dst,
                                     int unit_src, int unit_dst) {
  const float4 a = ((const float4*)src)[2 * unit_src];
  const float4 b = ((const float4*)src)[2 * unit_src + 1];
  half8 h;
  h[0] = (_Float16)a.x; h[1] = (_Float16)a.y; h[2] = (_Float16)a.z; h[3] = (_Float16)a.w;
  h[4] = (_Float16)b.x; h[5] = (_Float16)b.y; h[6] = (_Float16)b.z; h[7] = (_Float16)b.w;
  *(half8*)(dst + (size_t)unit_dst * 16) = h;
}

// units of 16B: xh 524288 | wqkvh 98304 | owh 32768 | rope 32768  = 688128 total
__global__ void prep(const float* __restrict__ x, const float* __restrict__ wqkv,
                     const float* __restrict__ ow, char* __restrict__ ws) {
  const int i = blockIdx.x * 256 + threadIdx.x;   // grid exactly covers 688128
  if (i < 524288) {                         // xh
    cvt8(x, ws, i, i);
  } else if (i < 622592) {                  // wqkvh
    const int o = i - 524288;
    cvt8(wqkv, ws + 8650752, o, o);
  } else if (i < 655360) {                  // owh
    const int o = i - 622592;
    cvt8(ow, ws + 10485760, o, o);
  } else {                                  // rope table: 2 entries per 16B unit
    const int u = i - 655360;
    float4 o4;
    {
      const int id = 2 * u, t = id >> 5, fi = id & 31;
      const float invf = powf(10000.0f, -(float)(2 * fi) * (1.0f / 64.0f));
      float s, c; sincosf((float)t * invf, &s, &c);
      o4.x = c; o4.y = s;
    }
    {
      const int id = 2 * u + 1, t = id >> 5, fi = id & 31;
      const float invf = powf(10000.0f, -(float)(2 * fi) * (1.0f / 64.0f));
      float s, c; sincosf((float)t * invf, &s, &c);
      o4.z = c; o4.w = s;
    }
    ((float4*)(ws + 46137344))[u] = o4;
  }
}

// ---------------- QKV GEMM (f16 MFMA) + fused RoPE -----------------------------
// R15 (kept): 512-thread blocks (8 waves) -> 24 waves/CU. Per wave: 32x128
// output, acc[2][4]. Staging = 1 DMA/thread per array. Dbuf pipeline.
__global__ __launch_bounds__(512) void qkv_gemm_mfma(
    const _Float16* __restrict__ A, const _Float16* __restrict__ B,
    const float2* __restrict__ rope,
    _Float16* __restrict__ qb, _Float16* __restrict__ kb, _Float16* __restrict__ vT)
{
  __shared__ __align__(16) _Float16 As0[128 * 32];
  __shared__ __align__(16) _Float16 Bs0[128 * 32];
  __shared__ __align__(16) _Float16 As1[128 * 32];
  __shared__ __align__(16) _Float16 Bs1[128 * 32];
  const int tid = threadIdx.x;
  const int wv = tid >> 6, lane = tid & 63, quad = lane >> 4, col = lane & 15;
  const int wm = wv >> 1, we = wv & 1;               // wm 0..3 (32-row), we 0..1 (64-col)
  const int m0 = blockIdx.x << 7, c0 = blockIdx.y << 7;
  const int r0 = tid >> 2, p0 = tid & 3;             // r0 0..127
  const int cA0 = (p0 - (r0 >> 1)) & 3;
  const _Float16* ga0 = &A[(size_t)(m0 + r0) * DM + cA0 * 8];
  const _Float16* gb0 = &B[(size_t)(c0 + r0) * DM + cA0 * 8];
  floatx4 acc[2][4] = {};   // [mt][et]

#define QKV_STAGE(AS, BS, K)                      \
  do {                                            \
    gl2lds16(ga0 + (K), &AS[tid * 8]);            \
    gl2lds16(gb0 + (K), &BS[tid * 8]);            \
  } while (0)

#define QKV_COMPUTE(AS, BS)                                                   \
  do {                                                                        \
    half8 af[2], bf[4];                                                       \
    _Pragma("unroll") for (int mt = 0; mt < 2; mt++) {                        \
      const int R = wm * 32 + mt * 16 + col;                                  \
      af[mt] = *(const half8*)&AS[R * 32 + (((quad + (R >> 1)) & 3) << 3)];   \
    }                                                                         \
    _Pragma("unroll") for (int et = 0; et < 4; et++) {                        \
      const int R = we * 64 + et * 16 + col;                                  \
      bf[et] = *(const half8*)&BS[R * 32 + (((quad + (R >> 1)) & 3) << 3)];   \
    }                                                                         \
    _Pragma("unroll") for (int mt = 0; mt < 2; mt++)                          \
      _Pragma("unroll") for (int et = 0; et < 4; et++)                        \
        acc[mt][et] =                                                         \
            __builtin_amdgcn_mfma_f32_16x16x32_f16(af[mt], bf[et], acc[mt][et], 0, 0, 0); \
  } while (0)

  QKV_STAGE(As0, Bs0, 0);       // prologue: tile 0 in flight
  for (int k0 = 0; k0 < DM; k0 += 64) {
    __syncthreads();                    // buf0(k0) landed & visible; prev reads done
    QKV_STAGE(As1, Bs1, k0 + 32);       // next tile flies under compute below
    QKV_COMPUTE(As0, Bs0);
    __syncthreads();                    // buf1 landed & visible; buf0 reads done
    if (k0 + 64 < DM) QKV_STAGE(As0, Bs0, k0 + 64);
    QKV_COMPUTE(As1, Bs1);
  }
#undef QKV_STAGE
#undef QKV_COMPUTE

  const int eidx = (c0 >> 6) + we;            // 0..23, wave-uniform
  const int three = eidx >> 3, h = eidx & 7;
  const int mbase = m0 + wm * 32 + quad * 4;
  if (three == 2) {
#pragma unroll
    for (int mt = 0; mt < 2; mt++) {
      const int m = mbase + mt * 16;
      const int n = m >> 11, t = m & 2047;
#pragma unroll
      for (int et = 0; et < 4; et++) {
        const int dh = et * 16 + col;
        half4 hv;
#pragma unroll
        for (int r = 0; r < 4; r++) hv[r] = (_Float16)acc[mt][et][r];
        *(half4*)&vT[(size_t)(n * NH + h) * HD * TSEQ + (size_t)dh * TSEQ + t] = hv;
      }
    }
  } else {
    _Float16* dst = three ? kb : qb;
    // q scale = (1/8) * log2(e) so attention's exp is a bare v_exp_f32
    const float scl = three ? 1.0f : 0.125f * 1.4426950408889634f;
#pragma unroll
    for (int mt = 0; mt < 2; mt++)
#pragma unroll
      for (int r = 0; r < 4; r++) {
        const int m = mbase + mt * 16 + r;
        const int n = m >> 11, t = m & 2047;
#pragma unroll
        for (int et = 0; et < 4; et++) {
          const int i = ((et & 1) << 4) + col;
          const float2 cs = rope[t * 32 + i];
          const float v = acc[mt][et][r];
          const float v2 = acc[mt][et ^ 2][r];
          const float o = (et < 2) ? (v * cs.x - v2 * cs.y) : (v * cs.x + v2 * cs.y);
          dst[((size_t)(n * NH + h) * TSEQ + t) * HD + et * 16 + col] = (_Float16)(o * scl);
        }
      }
  }
}

// ---------------- windowed flash attention, shift-free softmax ----------------
// R17: K/V staging via global_load_lds DMA + single-barrier double-buffer.
// The next tile's DMA is issued at the TOP of the iteration and lands
// asynchronously under the whole compute phase (qkv R8 pattern; R4's reg-stage
// failure mode -- ds_writes after compute -- doesn't exist with DMA). One
// __syncthreads per tile (drains vmcnt + flips buffers). DMA needs lane-linear
// LDS, so Ks/Vt drop the [72] pad and use a both-sides XOR swizzle (rule #21):
// stage source chunk = (tid&7) ^ (row&7); read granule g at slot g ^ (R&7).
// Bank pattern: 8 lanes per 16B slot-group x 8 groups = full 128 B/clk (same
// as the old padded layout). Ps/Osh alias (both wave-private rows) -> 50 KB.
__global__ __launch_bounds__(512, 4) void attn_win_mfma(
    const _Float16* __restrict__ qb, const _Float16* __restrict__ kb,
    const _Float16* __restrict__ vT, _Float16* __restrict__ ctx)
{
  __shared__ __align__(16) char smem[51200];
  _Float16* const KsA = (_Float16*)smem;               // [64][64] swizzled
  _Float16* const VtA = (_Float16*)(smem + 8192);      // [64][64] swizzled
  _Float16* const KsB = (_Float16*)(smem + 16384);
  _Float16* const VtB = (_Float16*)(smem + 24576);
  _Float16* const Ps  = (_Float16*)(smem + 32768);     // [128][72]; Osh aliases
  _Float16* const Osh = Ps;

  const int tid = threadIdx.x;
  const int wv = tid >> 6;                     // 0..7
  const int lane = tid & 63;
  const int quad = lane >> 4;
  const int col = lane & 15;
  // XCD swizzle: lin%8 = XCD -> 64 contiguous sl per XCD = 4 batch-heads
  const int lin = (blockIdx.y << 4) | blockIdx.x;          // 0..511
  const int sl  = ((lin & 7) << 6) | (lin >> 3);
  const int nh = sl >> 4;
  const int q0 = (sl & 15) << 7;
  const _Float16* qp = qb + (size_t)nh * TSEQ * HD;
  const _Float16* kp = kb + (size_t)nh * TSEQ * HD;
  const _Float16* vp = vT + (size_t)nh * HD * TSEQ;

  const int i_row = (wv << 4) + col;           // 0..127
  const int ig = q0 + i_row;
  const half8 qf0 = *(const half8*)&qp[(size_t)ig * HD + (quad << 3)];
  const half8 qf1 = *(const half8*)&qp[(size_t)ig * HD + 32 + (quad << 3)];

  float l_i = 0.0f;          // per-lane partial sum of p
  floatx4 accO[4] = {};

  const int kt0 = max(0, q0 - 127) >> 6;
  const int kt1 = min(TSEQ - 1, q0 + 255) >> 6;
  // DMA staging: 512 threads x 16B cover one 64x64 f16 tile.
  // srow = tile row; source chunk XOR-permuted so linear LDS = swizzled layout.
  const int srow = tid >> 3;                         // 0..63
  const int schunk = (tid & 7) ^ (srow & 7);         // 8-element granule index
  const _Float16* kpr = kp + (size_t)srow * HD + (schunk << 3);   // + j0*HD
  const _Float16* vpr = vp + (size_t)srow * TSEQ + (schunk << 3); // + j0
  const int iw0 = q0 + (wv << 4);                    // wave's first query

  // prologue: DMA first tile into buffer A
  {
    const int j0 = kt0 << 6;
    gl2lds16(kpr + (size_t)j0 * HD, KsA + tid * 8);
    gl2lds16(vpr + j0, VtA + tid * 8);
  }
  __syncthreads();

  int p = 0;
  for (int kt = kt0; kt <= kt1; kt++) {
    const int j0 = kt << 6;
    const _Float16* Ksc = p ? KsB : KsA;
    const _Float16* Vtc = p ? VtB : VtA;
    // issue next tile's DMA immediately: lands during the compute below
    if (kt < kt1) {
      const int jn = j0 + 64;
      gl2lds16(kpr + (size_t)jn * HD, (p ? KsA : KsB) + tid * 8);
      gl2lds16(vpr + jn, (p ? VtA : VtB) + tid * 8);
    }

    // wave-uniform whole-tile skip (as if-guard: barrier below stays uniform):
    // tile [j0, j0+63] intersects wave window [iw0-127, iw0+143]
    if ((unsigned)(j0 - iw0 + 190) < 334u) {
      // live(js): subtile [jlo, jlo+15] intersects [iw0-127, iw0+143]
      floatx4 S[4];
#pragma unroll
      for (int js = 0; js < 4; js++) {
        const int jlo = j0 + (js << 4);
        if ((unsigned)(jlo - iw0 + 142) < 286u) {
          const int R = (js << 4) + col;
          const half8 a0 = *(const half8*)&Ksc[R * 64 + ((quad ^ (R & 7)) << 3)];
          const half8 a1 = *(const half8*)&Ksc[R * 64 + (((quad + 4) ^ (R & 7)) << 3)];
          floatx4 c = {0.f, 0.f, 0.f, 0.f};
          c = __builtin_amdgcn_mfma_f32_16x16x32_f16(a0, qf0, c, 0, 0, 0);
          c = __builtin_amdgcn_mfma_f32_16x16x32_f16(a1, qf1, c, 0, 0, 0);
          S[js] = c;
        }
      }
      // mask -> p = exp2(s) (q carries log2e/8); masked p = 0.
      // window test: j in [ig-127, ig+128] <=> (unsigned)(j - ig + 127) < 256
      const int relb = j0 - ig + 127 + (quad << 2);
#pragma unroll
      for (int js = 0; js < 4; js++) {
        const int jlo = j0 + (js << 4);
        if ((unsigned)(jlo - iw0 + 142) < 286u) {
          half4 ph;
#pragma unroll
          for (int r = 0; r < 4; r++) {
            const bool valid = (unsigned)(relb + (js << 4) + r) < 256u;
            const float pv_ = valid ? EXP2F(S[js][r]) : 0.0f;
            l_i += pv_;
            ph[r] = (_Float16)pv_;
          }
          *(half4*)&Ps[i_row * 72 + (js << 4) + (quad << 2)] = ph;
        } else {
          const half4 zz = {(_Float16)0.f, (_Float16)0.f, (_Float16)0.f, (_Float16)0.f};
          *(half4*)&Ps[i_row * 72 + (js << 4) + (quad << 2)] = zz;
        }
      }
      // PV: Ps rows are wave-private; same-wave LDS ordering suffices.
      const half8 pa0 = *(const half8*)&Ps[i_row * 72 + (quad << 3)];
      const half8 pa1 = *(const half8*)&Ps[i_row * 72 + 32 + (quad << 3)];
#pragma unroll
      for (int d4 = 0; d4 < 4; d4++) {
        const int D = (d4 << 4) + col;
        const half8 vb0 = *(const half8*)&Vtc[D * 64 + ((quad ^ (D & 7)) << 3)];
        const half8 vb1 = *(const half8*)&Vtc[D * 64 + (((quad + 4) ^ (D & 7)) << 3)];
        accO[d4] = __builtin_amdgcn_mfma_f32_16x16x32_f16(pa0, vb0, accO[d4], 0, 0, 0);
        accO[d4] = __builtin_amdgcn_mfma_f32_16x16x32_f16(pa1, vb1, accO[d4], 0, 0, 0);
      }
    }
    __syncthreads();   // drains next-tile DMA + this tile's reads done
    p ^= 1;
  }
  // one cross-lane l reduction for the whole kernel (lanes sharing col = query)
  l_i += __shfl_xor(l_i, 16, 64);
  l_i += __shfl_xor(l_i, 32, 64);
  {
    const float linv = 1.0f / l_i;
    float l4[4];
#pragma unroll
    for (int r = 0; r < 4; r++) l4[r] = __shfl(linv, (quad << 2) + r, 64);
#pragma unroll
    for (int d4 = 0; d4 < 4; d4++)
#pragma unroll
      for (int r = 0; r < 4; r++)
        Osh[((wv << 4) + (quad << 2) + r) * 72 + (d4 << 4) + col] = (_Float16)(accO[d4][r] * l4[r]);
  }
  __syncthreads();
  {
    const int n = nh >> 3, h = nh & 7;
    const int oi = tid >> 2, oc = (tid & 3) << 4;    // 128 rows x 64 cols
    _Float16* dst = &ctx[((size_t)n * TSEQ + q0 + oi) * DM + h * HD + oc];
    *(half8*)&dst[0] = *(const half8*)&Osh[oi * 72 + oc];
    *(half8*)&dst[8] = *(const half8*)&Osh[oi * 72 + oc + 8];
  }
}

// ---------------- output projection (f16 MFMA) + bias, f32 out ------------------
// R16 (kept): 512-thread blocks, 8 waves each owning a 32x32 sub-tile.
__global__ __launch_bounds__(512) void out_gemm_mfma(
    const _Float16* __restrict__ A, const _Float16* __restrict__ B,
    const float* __restrict__ bias, float* __restrict__ out)
{
  __shared__ __align__(16) _Float16 As0[128 * 32];
  __shared__ __align__(16) _Float16 Bs0[64 * 32];
  __shared__ __align__(16) _Float16 As1[128 * 32];
  __shared__ __align__(16) _Float16 Bs1[64 * 32];
  const int tid = threadIdx.x;
  const int wv = tid >> 6, lane = tid & 63, quad = lane >> 4, col = lane & 15;
  const int wm = wv >> 1, we = wv & 1;               // wm 0..3 (32-row), we 0..1 (32-col)
  const int m0 = blockIdx.x << 7, c0 = blockIdx.y << 6;
  const int r0 = tid >> 2, p0 = tid & 3;             // A: r0 0..127
  const int cA0 = (p0 - (r0 >> 1)) & 3;
  const _Float16* ga0 = &A[(size_t)(m0 + r0) * DM + cA0 * 8];
  const _Float16* gb0 = &B[(size_t)(c0 + r0) * DM + cA0 * 8];   // valid for tid<256 (r0<64)
  floatx4 acc[2][2] = {};

#define OG_STAGE(AS, BS, K)                       \
  do {                                            \
    gl2lds16(ga0 + (K), &AS[tid * 8]);            \
    if (tid < 256) gl2lds16(gb0 + (K), &BS[tid * 8]); \
  } while (0)

#define OG_COMPUTE(AS, BS)                                                    \
  do {                                                                        \
    half8 af[2], bf[2];                                                       \
    _Pragma("unroll") for (int mt = 0; mt < 2; mt++) {                        \
      const int R = wm * 32 + mt * 16 + col;                                  \
      af[mt] = *(const half8*)&AS[R * 32 + (((quad + (R >> 1)) & 3) << 3)];   \
    }                                                                         \
    _Pragma("unroll") for (int et = 0; et < 2; et++) {                        \
      const int R = we * 32 + et * 16 + col;                                  \
      bf[et] = *(const half8*)&BS[R * 32 + (((quad + (R >> 1)) & 3) << 3)];   \
    }                                                                         \
    _Pragma("unroll") for (int mt = 0; mt < 2; mt++)                          \
      _Pragma("unroll") for (int et = 0; et < 2; et++)                        \
        acc[mt][et] =                                                         \
            __builtin_amdgcn_mfma_f32_16x16x32_f16(af[mt], bf[et], acc[mt][et], 0, 0, 0); \
  } while (0)

  OG_STAGE(As0, Bs0, 0);
  for (int k0 = 0; k0 < DM; k0 += 64) {
    __syncthreads();                    // buf0(k0) landed & visible; prev reads done
    OG_STAGE(As1, Bs1, k0 + 32);
    OG_COMPUTE(As0, Bs0);
    __syncthreads();
    if (k0 + 64 < DM) OG_STAGE(As0, Bs0, k0 + 64);
    OG_COMPUTE(As1, Bs1);
  }
#undef OG_STAGE
#undef OG_COMPUTE

  float bb[2];
#pragma unroll
  for (int et = 0; et < 2; et++) bb[et] = bias[c0 + we * 32 + et * 16 + col];
  const int mbase = m0 + wm * 32 + quad * 4;
#pragma unroll
  for (int mt = 0; mt < 2; mt++)
#pragma unroll
    for (int r = 0; r < 4; r++) {
      const int m = mbase + mt * 16 + r;
#pragma unroll
      for (int et = 0; et < 2; et++)
        out[(size_t)m * DM + c0 + we * 32 + et * 16 + col] = acc[mt][et][r] + bb[et];
    }
}

extern "C" void kernel_launch(void* const* d_in, const int* in_sizes, int n_in,
                              void* d_out, int out_size, void* d_ws, size_t ws_size,
                              hipStream_t stream) {
  const float* x    = (const float*)d_in[0];
  const float* wqkv = (const float*)d_in[1];
  const float* ow   = (const float*)d_in[2];
  const float* ob   = (const float*)d_in[3];
  char* ws = (char*)d_ws;
  _Float16* xh    = (_Float16*)(ws);               //  8,388,608 B
  _Float16* wqkvh = (_Float16*)(ws + 8650752);     //  1,572,864 B
  _Float16* owh   = (_Float16*)(ws + 10485760);    //    524,288 B
  _Float16* qbuf  = (_Float16*)(ws + 11534336);    //  8,388,608 B
  _Float16* kbuf  = (_Float16*)(ws + 20971520);    //  8,388,608 B
  _Float16* vTb   = (_Float16*)(ws + 29360128);    //  8,388,608 B
  _Float16* ctxh  = (_Float16*)(ws + 37748736);    //  8,388,608 B
  float2*   rope  = (float2*)  (ws + 46137344);    //    524,288 B -> end 46,661,632

  prep<<<2688, 256, 0, stream>>>(x, wqkv, ow, ws);        // 688128 16B-units
  qkv_gemm_mfma<<<dim3(64, 12), 512, 0, stream>>>(xh, wqkvh, rope, qbuf, kbuf, vTb);
  attn_win_mfma<<<dim3(16, 32), 512, 0, stream>>>(qbuf, kbuf, vTb, ctxh);
  out_gemm_mfma<<<dim3(64, 8), 512, 0, stream>>>(ctxh, owh, ob, (float*)d_out);
}